// Round 3
// baseline (35091.415 us; speedup 1.0000x reference)
//
#include <hip/hip_runtime.h>
#include <hip/hip_fp16.h>
#include <cmath>

// ---------------------------------------------------------------------------
// LMU fused recurrence.  Merged formulation: one 128x1536 @ 1536x1536 GEMM per
// step (tanh on first 1024 cols, linear on last 512), x-dependent rank-1 bias.
// Persistent kernel (plain launch, 192 WGs <= 256 CUs, co-resident by VGPR
// pressure), 2 independent batch groups x 96 WGs, one agent-scope barrier per
// step per group, double-buffered state in __device__ globals (no d_ws use).
// Precision: f16 hi/lo for weights AND state (lo planes scaled x2048 to stay
// in f16 normal range), fp32 MFMA accumulate, 3 products:
//   Ah*Wh + (Al'*Wh + Ah*Wl')/2048   ->  ~2^-22 effective.
// W_hi in LDS (48 KB static), W_lo register-resident (192 VGPR/lane).
// ---------------------------------------------------------------------------

typedef _Float16 half8 __attribute__((ext_vector_type(8)));
typedef float floatx4 __attribute__((ext_vector_type(4)));

#define NSTATE   1536
#define BATCH    128
#define TSTEPS   784
#define KTILES   48                 // 1536 / 32
#define GRP_WGS  96                 // WGs per batch group
#define WPW      24576              // weight elems per WG slice (16 cols * 1536)
#define LO_SCALE 2048.0f
#define LO_INV   (1.0f / 2048.0f)

// All scratch in device globals: no dependence on ws_size, no hipMalloc.
__device__ __align__(16) _Float16 g_Whi[96 * WPW];
__device__ __align__(16) _Float16 g_Wlo[96 * WPW];
__device__ float    g_wb[NSTATE];
__device__ float    g_WmA[1024 * 512];
__device__ float    g_WmB[1024];
__device__ __align__(16) _Float16 g_Shi[2 * BATCH * NSTATE];
__device__ __align__(16) _Float16 g_Slo[2 * BATCH * NSTATE];
__device__ unsigned g_bar[256];

// W_mB[i] = sum_c W_m[i,c] * BT[c]   (one wave per row, shuffle reduce)
__global__ void prep_wmb(const float* __restrict__ Wm, const float* __restrict__ BT) {
    int row  = blockIdx.x * 4 + (threadIdx.x >> 6);
    int lane = threadIdx.x & 63;
    float s = 0.f;
    for (int c = lane; c < 512; c += 64) s += Wm[row * 512 + c] * BT[c];
    for (int o = 32; o; o >>= 1) s += __shfl_down(s, o);
    if (lane == 0) g_WmB[row] = s;
}

// W_mA = W_m @ (I + AT) : tiled 32x32, fp32
__global__ void prep_wma(const float* __restrict__ Wm, const float* __restrict__ AT) {
    __shared__ float As[32][33], Bs[32][33];
    int d0 = blockIdx.x * 32, i0 = blockIdx.y * 32;
    int tx = threadIdx.x & 31, ty = threadIdx.x >> 5;   // ty in 0..7
    float acc[4];
#pragma unroll
    for (int r = 0; r < 4; ++r) acc[r] = Wm[(i0 + ty + 8 * r) * 512 + d0 + tx];
    for (int c0 = 0; c0 < 512; c0 += 32) {
#pragma unroll
        for (int r = 0; r < 4; ++r) {
            As[ty + 8 * r][tx] = Wm[(i0 + ty + 8 * r) * 512 + c0 + tx];
            Bs[ty + 8 * r][tx] = AT[(c0 + ty + 8 * r) * 512 + d0 + tx];
        }
        __syncthreads();
#pragma unroll
        for (int c = 0; c < 32; ++c)
#pragma unroll
            for (int r = 0; r < 4; ++r) acc[r] += As[ty + 8 * r][c] * Bs[c][tx];
        __syncthreads();
    }
#pragma unroll
    for (int r = 0; r < 4; ++r) g_WmA[(i0 + ty + 8 * r) * 512 + d0 + tx] = acc[r];
}

// Build W_full in MFMA-B-fragment-swizzled order, split f16 hi/lo (lo x2048).
// Also: wb vector, zero state buffers, zero barrier counters.
// swizzled index s = ((p*48 + kt)*64 + lane)*8 + j
//   n = p*16 + (lane&15),  k = kt*32 + ((lane>>4)&3)*8 + j
__global__ void prep_wfull(const float* __restrict__ Wh, const float* __restrict__ AT,
                           const float* __restrict__ BT, const float* __restrict__ eh,
                           const float* __restrict__ em, const float* __restrict__ ex,
                           const float* __restrict__ Wx) {
    int s = blockIdx.x * 256 + threadIdx.x;     // [0, 96*48*64*8) exactly
    int j8 = s & 7;
    int t = s >> 3;
    int lane = t & 63;
    t >>= 6;
    int kt = t % 48;
    int p = t / 48;
    int n = p * 16 + (lane & 15);
    int k = kt * 32 + ((lane >> 4) & 3) * 8 + j8;

    float w;
    if (n < 1024) {
        if (k < 1024) w = Wh[n * 1024 + k] + g_WmB[n] * eh[k];
        else          w = g_WmA[n * 512 + (k - 1024)] + g_WmB[n] * em[k - 1024];
    } else {
        int c = n - 1024;
        if (k < 1024) w = BT[c] * eh[k];
        else {
            int d = k - 1024;
            w = ((c == d) ? 1.f : 0.f) + AT[c * 512 + d] + BT[c] * em[d];
        }
    }
    _Float16 hi = (_Float16)w;
    g_Whi[s] = hi;
    g_Wlo[s] = (_Float16)((w - (float)hi) * LO_SCALE);

    if (s < NSTATE) {
        float b = (s < 1024) ? (Wx[s] + ex[0] * g_WmB[s]) : (BT[s - 1024] * ex[0]);
        g_wb[s] = b;
    }
    if (s < 2 * BATCH * NSTATE) { g_Shi[s] = (_Float16)0.f; g_Slo[s] = (_Float16)0.f; }
    if (s < 256) g_bar[s] = 0u;
}

__launch_bounds__(256, 1)
__global__ void lmu_persist(const float* __restrict__ inputs,
                            const float* __restrict__ Wd, const float* __restrict__ bd,
                            float* __restrict__ out) {
    __shared__ half8 lw[KTILES * 64];           // W_hi slice: 48 KB

    const int tid = threadIdx.x;
    const int bid = blockIdx.x;
    const int g = (bid >> 2) & 1;               // batch group
    const int p = (bid >> 3) * 4 + (bid & 3);   // column tile [0,96)

    // stage W_hi (global, swizzled-linear) -> LDS
    {
        const half8* src = (const half8*)(g_Whi + (size_t)p * WPW);
        for (int i = tid; i < WPW / 8; i += 256) lw[i] = src[i];
    }

    const int lane = tid & 63, wv = tid >> 6;
    const int quad = lane >> 4, l16 = lane & 15;
    const int b0 = g * 64 + wv * 16;            // this wave's 16-row block
    const int n = p * 16 + l16;                 // this lane's output column
    const float wbv = g_wb[n];
    const bool do_tanh = (p < 64);
    unsigned* cnt = g_bar + (g ? 128 : 0);
    unsigned* gen = g_bar + (g ? 192 : 64);

    // W_lo slice: register-resident (48 * half8 = 192 VGPRs/lane)
    half8 wlo[KTILES];
    {
        const half8* src = (const half8*)(g_Wlo + (size_t)p * WPW);
#pragma unroll
        for (int q = 0; q < KTILES; ++q) wlo[q] = src[q * 64 + lane];
    }
    __syncthreads();

    const int rowA = b0 + l16;                  // A-fragment row for this lane
    const int kbase = quad * 8;

    int buf = 0;
    for (int t = 0; t < TSTEPS; ++t) {
        const _Float16* shr = g_Shi + buf * BATCH * NSTATE + rowA * NSTATE + kbase;
        const _Float16* slr = g_Slo + buf * BATCH * NSTATE + rowA * NSTATE + kbase;

        // x_t for epilogue
        const float* xt = inputs + t * BATCH;
        float xv[4];
#pragma unroll
        for (int r = 0; r < 4; ++r) xv[r] = xt[b0 + quad * 4 + r];

        floatx4 aA[2], aB[2], aC[2];
#pragma unroll
        for (int q = 0; q < 2; ++q) { aA[q] = (floatx4)0.f; aB[q] = (floatx4)0.f; aC[q] = (floatx4)0.f; }

#pragma unroll
        for (int kt = 0; kt < KTILES; ++kt) {
            half8 ah = *(const half8*)(shr + kt * 32);
            half8 al = *(const half8*)(slr + kt * 32);
            half8 bh = lw[kt * 64 + lane];
            aA[kt & 1] = __builtin_amdgcn_mfma_f32_16x16x32_f16(ah, bh, aA[kt & 1], 0, 0, 0);
            aB[kt & 1] = __builtin_amdgcn_mfma_f32_16x16x32_f16(al, bh, aB[kt & 1], 0, 0, 0);
            aC[kt & 1] = __builtin_amdgcn_mfma_f32_16x16x32_f16(ah, wlo[kt], aC[kt & 1], 0, 0, 0);
        }

        // epilogue: bias + activation, split to f16 hi/lo (lo x2048), write next buf
        const int nbuf = buf ^ 1;
        _Float16* dh = g_Shi + nbuf * BATCH * NSTATE;
        _Float16* dl = g_Slo + nbuf * BATCH * NSTATE;
#pragma unroll
        for (int r = 0; r < 4; ++r) {
            int b = b0 + quad * 4 + r;
            float v = (aA[0][r] + aA[1][r])
                    + ((aB[0][r] + aB[1][r]) + (aC[0][r] + aC[1][r])) * LO_INV;
            v += xv[r] * wbv;
            if (do_tanh) v = tanhf(v);
            _Float16 hi = (_Float16)v;
            dh[b * NSTATE + n] = hi;
            dl[b * NSTATE + n] = (_Float16)((v - (float)hi) * LO_SCALE);
        }

        // ---- group barrier (generation counter, agent scope) ----
        __builtin_amdgcn_fence(__ATOMIC_RELEASE, "agent");   // push this wave's stores
        __syncthreads();
        if (tid == 0) {
            unsigned old = __hip_atomic_fetch_add(cnt, 1u, __ATOMIC_ACQ_REL,
                                                  __HIP_MEMORY_SCOPE_AGENT);
            if (old == (unsigned)(GRP_WGS - 1)) {
                __hip_atomic_store(cnt, 0u, __ATOMIC_RELAXED, __HIP_MEMORY_SCOPE_AGENT);
                __hip_atomic_fetch_add(gen, 1u, __ATOMIC_RELEASE,
                                       __HIP_MEMORY_SCOPE_AGENT);
            } else {
                int spin = 0;
                while (__hip_atomic_load(gen, __ATOMIC_ACQUIRE,
                                         __HIP_MEMORY_SCOPE_AGENT) < (unsigned)(t + 1)) {
                    __builtin_amdgcn_s_sleep(2);
                    if (++spin > (1 << 18)) break;          // deadman: no hang
                }
            }
            __builtin_amdgcn_fence(__ATOMIC_ACQUIRE, "agent");
        }
        __syncthreads();
        __builtin_amdgcn_fence(__ATOMIC_ACQUIRE, "agent");   // invalidate stale L1/L2
        buf = nbuf;
    }

    // final epilogue: logits + softmax. WGs p<64 each own one batch row. buf==0.
    if (p < 64) {
        int b = g * 64 + p;
        const _Float16* sh = g_Shi + b * NSTATE;
        const _Float16* sl = g_Slo + b * NSTATE;
        __syncthreads();                         // smem reuse
        float* red = (float*)lw;                 // [16 chunks][16 cols] + [10 logits]
        int c = tid & 15, chunk = tid >> 4;
        float part = 0.f;
        if (c < 10) {
            for (int i = chunk * 64; i < chunk * 64 + 64; ++i)
                part += ((float)sh[i] + (float)sl[i] * LO_INV) * Wd[c * 1024 + i];
        }
        red[chunk * 16 + c] = part;
        __syncthreads();
        if (tid < 10) {
            float lg = bd[tid];
            for (int q = 0; q < 16; ++q) lg += red[q * 16 + tid];
            red[256 + tid] = lg;
        }
        __syncthreads();
        if (tid < 10) {
            float mx = red[256];
            for (int q = 1; q < 10; ++q) mx = fmaxf(mx, red[256 + q]);
            float sm = 0.f;
            for (int q = 0; q < 10; ++q) sm += expf(red[256 + q] - mx);
            out[b * 10 + tid] = expf(red[256 + tid] - mx) / sm;
        }
    }
}

extern "C" void kernel_launch(void* const* d_in, const int* in_sizes, int n_in,
                              void* d_out, int out_size, void* d_ws, size_t ws_size,
                              hipStream_t stream) {
    const float* inputs = (const float*)d_in[0];
    const float* e_x    = (const float*)d_in[1];
    const float* e_h    = (const float*)d_in[2];
    const float* e_m    = (const float*)d_in[3];
    const float* W_x    = (const float*)d_in[4];
    const float* W_h    = (const float*)d_in[5];
    const float* W_m    = (const float*)d_in[6];
    const float* AT     = (const float*)d_in[7];
    const float* BT     = (const float*)d_in[8];
    const float* W_d    = (const float*)d_in[9];
    const float* b_d    = (const float*)d_in[10];
    (void)d_ws; (void)ws_size; (void)in_sizes; (void)n_in;

    prep_wmb<<<256, 256, 0, stream>>>(W_m, BT);
    prep_wma<<<dim3(16, 32), 256, 0, stream>>>(W_m, AT);
    prep_wfull<<<9216, 256, 0, stream>>>(W_h, AT, BT, e_h, e_m, e_x, W_x);

    lmu_persist<<<192, 256, 0, stream>>>(inputs, W_d, b_d, (float*)d_out);
}

// Round 4
// 16790.393 us; speedup vs baseline: 2.0900x; 2.0900x over previous
//
#include <hip/hip_runtime.h>
#include <hip/hip_fp16.h>
#include <cmath>

// ---------------------------------------------------------------------------
// LMU fused recurrence.  Merged formulation: one 128x1536 @ 1536x1536 GEMM per
// step (tanh on first 1024 cols, linear on last 512), x-dependent rank-1 bias.
// Persistent kernel, 192 WGs x 256 thr (1 WG/CU), 2 independent batch groups
// x 96 WGs, one agent-scope barrier per step per group, double-buffered state
// in __device__ globals.
// Precision (verified r3, absmax 4.9e-4): f16 hi/lo for weights AND state
// (lo planes scaled x2048), fp32 MFMA accumulate, 3 products:
//   Ah*Wh + (Al'*Wh + Ah*Wl')/2048  -> ~2^-22 effective.
// r4 changes: W_lo in LDS (was register array -> compiler spilled, VGPR=132);
// barrier spin uses RELAXED polls (ACQUIRE-per-poll invalidated whole XCD L2
// every iteration -> 35ms). One acquire fence per step after spin exit.
// ---------------------------------------------------------------------------

typedef _Float16 half8 __attribute__((ext_vector_type(8)));
typedef float floatx4 __attribute__((ext_vector_type(4)));

#define NSTATE   1536
#define BATCH    128
#define TSTEPS   784
#define KTILES   48                 // 1536 / 32
#define GRP_WGS  96                 // WGs per batch group
#define WPW      24576              // weight elems per WG slice (16 cols * 1536)
#define LO_SCALE 2048.0f
#define LO_INV   (1.0f / 2048.0f)

// All scratch in device globals: no dependence on ws_size, no hipMalloc.
__device__ __align__(16) _Float16 g_Whi[96 * WPW];
__device__ __align__(16) _Float16 g_Wlo[96 * WPW];
__device__ float    g_wb[NSTATE];
__device__ float    g_WmA[1024 * 512];
__device__ float    g_WmB[1024];
__device__ __align__(16) _Float16 g_Shi[2 * BATCH * NSTATE];
__device__ __align__(16) _Float16 g_Slo[2 * BATCH * NSTATE];
__device__ unsigned g_bar[256];

// W_mB[i] = sum_c W_m[i,c] * BT[c]   (one wave per row, shuffle reduce)
__global__ void prep_wmb(const float* __restrict__ Wm, const float* __restrict__ BT) {
    int row  = blockIdx.x * 4 + (threadIdx.x >> 6);
    int lane = threadIdx.x & 63;
    float s = 0.f;
    for (int c = lane; c < 512; c += 64) s += Wm[row * 512 + c] * BT[c];
    for (int o = 32; o; o >>= 1) s += __shfl_down(s, o);
    if (lane == 0) g_WmB[row] = s;
}

// W_mA = W_m @ (I + AT) : tiled 32x32, fp32
__global__ void prep_wma(const float* __restrict__ Wm, const float* __restrict__ AT) {
    __shared__ float As[32][33], Bs[32][33];
    int d0 = blockIdx.x * 32, i0 = blockIdx.y * 32;
    int tx = threadIdx.x & 31, ty = threadIdx.x >> 5;   // ty in 0..7
    float acc[4];
#pragma unroll
    for (int r = 0; r < 4; ++r) acc[r] = Wm[(i0 + ty + 8 * r) * 512 + d0 + tx];
    for (int c0 = 0; c0 < 512; c0 += 32) {
#pragma unroll
        for (int r = 0; r < 4; ++r) {
            As[ty + 8 * r][tx] = Wm[(i0 + ty + 8 * r) * 512 + c0 + tx];
            Bs[ty + 8 * r][tx] = AT[(c0 + ty + 8 * r) * 512 + d0 + tx];
        }
        __syncthreads();
#pragma unroll
        for (int c = 0; c < 32; ++c)
#pragma unroll
            for (int r = 0; r < 4; ++r) acc[r] += As[ty + 8 * r][c] * Bs[c][tx];
        __syncthreads();
    }
#pragma unroll
    for (int r = 0; r < 4; ++r) g_WmA[(i0 + ty + 8 * r) * 512 + d0 + tx] = acc[r];
}

// Build W_full in MFMA-B-fragment-swizzled order, split f16 hi/lo (lo x2048).
// Also: wb vector, zero state buffers, zero barrier counters.
// swizzled index s = ((p*48 + kt)*64 + lane)*8 + j
//   n = p*16 + (lane&15),  k = kt*32 + ((lane>>4)&3)*8 + j
__global__ void prep_wfull(const float* __restrict__ Wh, const float* __restrict__ AT,
                           const float* __restrict__ BT, const float* __restrict__ eh,
                           const float* __restrict__ em, const float* __restrict__ ex,
                           const float* __restrict__ Wx) {
    int s = blockIdx.x * 256 + threadIdx.x;     // [0, 96*48*64*8) exactly
    int j8 = s & 7;
    int t = s >> 3;
    int lane = t & 63;
    t >>= 6;
    int kt = t % 48;
    int p = t / 48;
    int n = p * 16 + (lane & 15);
    int k = kt * 32 + ((lane >> 4) & 3) * 8 + j8;

    float w;
    if (n < 1024) {
        if (k < 1024) w = Wh[n * 1024 + k] + g_WmB[n] * eh[k];
        else          w = g_WmA[n * 512 + (k - 1024)] + g_WmB[n] * em[k - 1024];
    } else {
        int c = n - 1024;
        if (k < 1024) w = BT[c] * eh[k];
        else {
            int d = k - 1024;
            w = ((c == d) ? 1.f : 0.f) + AT[c * 512 + d] + BT[c] * em[d];
        }
    }
    _Float16 hi = (_Float16)w;
    g_Whi[s] = hi;
    g_Wlo[s] = (_Float16)((w - (float)hi) * LO_SCALE);

    if (s < NSTATE) {
        float b = (s < 1024) ? (Wx[s] + ex[0] * g_WmB[s]) : (BT[s - 1024] * ex[0]);
        g_wb[s] = b;
    }
    if (s < 2 * BATCH * NSTATE) { g_Shi[s] = (_Float16)0.f; g_Slo[s] = (_Float16)0.f; }
    if (s < 256) g_bar[s] = 0u;
}

__launch_bounds__(256, 1)
__global__ void lmu_persist(const float* __restrict__ inputs,
                            const float* __restrict__ Wd, const float* __restrict__ bd,
                            float* __restrict__ out) {
    __shared__ half8 lwh[KTILES * 64];          // W_hi slice: 48 KB
    __shared__ half8 lwl[KTILES * 64];          // W_lo slice: 48 KB (96 KB total)

    const int tid = threadIdx.x;
    const int bid = blockIdx.x;
    const int g = (bid >> 2) & 1;               // batch group
    const int p = (bid >> 3) * 4 + (bid & 3);   // column tile [0,96)

    // stage W_hi + W_lo (global, swizzled-linear) -> LDS
    {
        const half8* srcH = (const half8*)(g_Whi + (size_t)p * WPW);
        const half8* srcL = (const half8*)(g_Wlo + (size_t)p * WPW);
        for (int i = tid; i < WPW / 8; i += 256) { lwh[i] = srcH[i]; lwl[i] = srcL[i]; }
    }

    const int lane = tid & 63, wv = tid >> 6;
    const int quad = lane >> 4, l16 = lane & 15;
    const int b0 = g * 64 + wv * 16;            // this wave's 16-row block
    const int n = p * 16 + l16;                 // this lane's output column
    const float wbv = g_wb[n];
    const bool do_tanh = (p < 64);
    unsigned* cnt = g_bar + g * 128;
    unsigned* gen = g_bar + g * 128 + 64;

    __syncthreads();

    const int rowA = b0 + l16;                  // A-fragment row for this lane
    const int kbase = quad * 8;

    int buf = 0;
    for (int t = 0; t < TSTEPS; ++t) {
        const _Float16* shr = g_Shi + buf * BATCH * NSTATE + rowA * NSTATE + kbase;
        const _Float16* slr = g_Slo + buf * BATCH * NSTATE + rowA * NSTATE + kbase;

        // x_t for epilogue
        const float* xt = inputs + t * BATCH;
        float xv[4];
#pragma unroll
        for (int r = 0; r < 4; ++r) xv[r] = xt[b0 + quad * 4 + r];

        floatx4 aA[2], aB[2], aC[2];
#pragma unroll
        for (int q = 0; q < 2; ++q) { aA[q] = (floatx4)0.f; aB[q] = (floatx4)0.f; aC[q] = (floatx4)0.f; }

#pragma unroll
        for (int kt = 0; kt < KTILES; ++kt) {
            half8 ah = *(const half8*)(shr + kt * 32);
            half8 al = *(const half8*)(slr + kt * 32);
            half8 bh = lwh[kt * 64 + lane];
            half8 bl = lwl[kt * 64 + lane];
            aA[kt & 1] = __builtin_amdgcn_mfma_f32_16x16x32_f16(ah, bh, aA[kt & 1], 0, 0, 0);
            aB[kt & 1] = __builtin_amdgcn_mfma_f32_16x16x32_f16(al, bh, aB[kt & 1], 0, 0, 0);
            aC[kt & 1] = __builtin_amdgcn_mfma_f32_16x16x32_f16(ah, bl, aC[kt & 1], 0, 0, 0);
        }

        // epilogue: bias + activation, split to f16 hi/lo (lo x2048), write next buf
        const int nbuf = buf ^ 1;
        _Float16* dh = g_Shi + nbuf * BATCH * NSTATE;
        _Float16* dl = g_Slo + nbuf * BATCH * NSTATE;
#pragma unroll
        for (int r = 0; r < 4; ++r) {
            int b = b0 + quad * 4 + r;
            float v = (aA[0][r] + aA[1][r])
                    + ((aB[0][r] + aB[1][r]) + (aC[0][r] + aC[1][r])) * LO_INV;
            v += xv[r] * wbv;
            if (do_tanh) v = tanhf(v);
            _Float16 hi = (_Float16)v;
            dh[b * NSTATE + n] = hi;
            dl[b * NSTATE + n] = (_Float16)((v - (float)hi) * LO_SCALE);
        }

        // ---- group barrier: relaxed polls, ONE acquire fence per step ----
        __syncthreads();                        // drains vmcnt: WG stores in L2
        if (tid == 0) {
            __builtin_amdgcn_fence(__ATOMIC_RELEASE, "agent");  // wbl2: L2 -> LLC
            unsigned old = __hip_atomic_fetch_add(cnt, 1u, __ATOMIC_RELAXED,
                                                  __HIP_MEMORY_SCOPE_AGENT);
            if (old == (unsigned)(GRP_WGS - 1)) {
                __hip_atomic_store(cnt, 0u, __ATOMIC_RELAXED, __HIP_MEMORY_SCOPE_AGENT);
                __hip_atomic_fetch_add(gen, 1u, __ATOMIC_RELEASE,
                                       __HIP_MEMORY_SCOPE_AGENT);
            } else {
                int spin = 0;
                // RELAXED poll: reads coherent point, no cache invalidate
                while (__hip_atomic_load(gen, __ATOMIC_RELAXED,
                                         __HIP_MEMORY_SCOPE_AGENT) < (unsigned)(t + 1)) {
                    __builtin_amdgcn_s_sleep(1);
                    if (++spin > (1 << 19)) break;          // deadman: no hang
                }
            }
            __builtin_amdgcn_fence(__ATOMIC_ACQUIRE, "agent");  // inv L1+L2, once
        }
        __syncthreads();
        buf = nbuf;
    }

    // final epilogue: logits + softmax. WGs p<64 each own one batch row. buf==0.
    if (p < 64) {
        int b = g * 64 + p;
        const _Float16* sh = g_Shi + b * NSTATE;
        const _Float16* sl = g_Slo + b * NSTATE;
        __syncthreads();                         // smem reuse
        float* red = (float*)lwh;                // [16 chunks][16 cols] + [10 logits]
        int c = tid & 15, chunk = tid >> 4;
        float part = 0.f;
        if (c < 10) {
            for (int i = chunk * 64; i < chunk * 64 + 64; ++i)
                part += ((float)sh[i] + (float)sl[i] * LO_INV) * Wd[c * 1024 + i];
        }
        red[chunk * 16 + c] = part;
        __syncthreads();
        if (tid < 10) {
            float lg = bd[tid];
            for (int q = 0; q < 16; ++q) lg += red[q * 16 + tid];
            red[256 + tid] = lg;
        }
        __syncthreads();
        if (tid < 10) {
            float mx = red[256];
            for (int q = 1; q < 10; ++q) mx = fmaxf(mx, red[256 + q]);
            float sm = 0.f;
            for (int q = 0; q < 10; ++q) sm += expf(red[256 + q] - mx);
            out[b * 10 + tid] = expf(red[256 + tid] - mx) / sm;
        }
    }
}

extern "C" void kernel_launch(void* const* d_in, const int* in_sizes, int n_in,
                              void* d_out, int out_size, void* d_ws, size_t ws_size,
                              hipStream_t stream) {
    const float* inputs = (const float*)d_in[0];
    const float* e_x    = (const float*)d_in[1];
    const float* e_h    = (const float*)d_in[2];
    const float* e_m    = (const float*)d_in[3];
    const float* W_x    = (const float*)d_in[4];
    const float* W_h    = (const float*)d_in[5];
    const float* W_m    = (const float*)d_in[6];
    const float* AT     = (const float*)d_in[7];
    const float* BT     = (const float*)d_in[8];
    const float* W_d    = (const float*)d_in[9];
    const float* b_d    = (const float*)d_in[10];
    (void)d_ws; (void)ws_size; (void)in_sizes; (void)n_in;

    prep_wmb<<<256, 256, 0, stream>>>(W_m, BT);
    prep_wma<<<dim3(16, 32), 256, 0, stream>>>(W_m, AT);
    prep_wfull<<<9216, 256, 0, stream>>>(W_h, AT, BT, e_h, e_m, e_x, W_x);

    lmu_persist<<<192, 256, 0, stream>>>(inputs, W_d, b_d, (float*)d_out);
}